// Round 9
// baseline (485.082 us; speedup 1.0000x reference)
//
#include <hip/hip_runtime.h>

// MPNN sparse on MI355X (fp32 I/O, bf16 MFMA compute).
// R9: algebraic restructure of the edge stage.
//   agg[t] = (Σ_s relu(P'[t]+Q[s])) @ W2 + cnt[t]*b2   (W2 linearity)
//   edge3: pure streaming segmented reduction into Hsum (fp32, N x 256):
//          P' register-cached per target run, Q 8B/lane coalesced, no LDS,
//          no MFMA, 8 blocks/CU. 16x less edge-level GEMM work.
//   node2: fuses Hsum@W2 + cnt*b2 (message W2) in front of the node MLP.
// Fallback to the verified R8 path if ws_size < ~121 MB (R8 needs ~95 MB).

#define N_NODES 50000
#define E_EDGES 800000
#define DF   144
#define DIN  128
#define DDEG 16
#define DMSG 128
#define SA_LD 296     // 288 + 8 pad (shorts)
#define SH_LD 264     // 256 + 8 pad (shorts)
#define PQ_LD 512     // P'(256) | Q(256) per node, bf16
#define KA_LD 168     // 160 + 8 pad (pq A staging)
#define MSG_LD 130    // 128 + 2 pad (fp32 msg buffer, fallback)
#define NSCAN 50176   // 196 * 256
#define NBLK_SCAN 196
#define PQ_BLOCKS 782     // ceil(50000/64)
#define HIST_BLOCKS 3125  // 800000/256
#define PACK_THREADS 27648

typedef __attribute__((ext_vector_type(8))) short short8;
typedef __attribute__((ext_vector_type(4))) float floatx4;

__device__ __forceinline__ unsigned int fasu(float f){
  union { float f; unsigned int u; } v; v.f = f; return v.u;
}
__device__ __forceinline__ float uasf(unsigned int u){
  union { unsigned int u; float f; } v; v.u = u; return v.f;
}
__device__ __forceinline__ short f2bf(float f){           // RNE
  unsigned int i = fasu(f);
  unsigned int r = i + 0x7fffu + ((i >> 16) & 1u);
  return (short)(r >> 16);
}
__device__ __forceinline__ unsigned int pk_trunc(float lo, float hi){
  return __builtin_amdgcn_perm(fasu(hi), fasu(lo), 0x07060302u);
}
__device__ __forceinline__ unsigned int addrelu_pk(unsigned int u, unsigned int v){
  float lo = uasf(u << 16) + uasf(v << 16);
  float hi = uasf(u & 0xffff0000u) + uasf(v & 0xffff0000u);
  lo = lo > 0.0f ? lo : 0.0f;
  hi = hi > 0.0f ? hi : 0.0f;
  return pk_trunc(lo, hi);
}

// ---- sentinel ----
__global__ void sentinel_kernel(float* __restrict__ out){
  int i = blockIdx.x * blockDim.x + threadIdx.x;
  if (i < N_NODES * DMSG){ out[i] = 2.0f; }
}

// ---- prep: zero zb (float4 units), cnt=0, h=bf16([x|deg]) ----
__global__ void prep_kernel(const float* __restrict__ x, const float* __restrict__ deg,
                            float4* __restrict__ zb, int nzf4,
                            int* __restrict__ cnt, short* __restrict__ h){
  int i = blockIdx.x * blockDim.x + threadIdx.x;
  if (i < nzf4){
    float4 z; z.x = 0.0f; z.y = 0.0f; z.z = 0.0f; z.w = 0.0f;
    zb[i] = z;
  }
  if (i < NSCAN){ cnt[i] = 0; }
  if (i < N_NODES * 18){
    int n = i / 18;
    int j = i - n * 18;
    const float* src;
    if (j < 16){ src = x + (size_t)n * DIN + (size_t)j * 8; }
    else       { src = deg + (size_t)n * DDEG + (size_t)(j - 16) * 8; }
    short8 v;
    for (int t = 0; t < 8; ++t){ v[t] = f2bf(src[t]); }
    *(short8*)(h + (size_t)n * DF + (size_t)j * 8) = v;
  }
}

// ---- pack helpers ----
__device__ __forceinline__ void pack_w_dev(const float* __restrict__ W,
                                           short* __restrict__ Wp,
                                           int Ksrc, int nT, int t){
  int lane = t & 63;
  int rest = t >> 6;
  int nt = rest % nT;
  int chunk = rest / nT;
  int Ncols = nT * 16;
  int n = nt * 16 + (lane & 15);
  int kbase = chunk * 32 + (lane >> 4) * 8;
  short8 v;
  for (int j = 0; j < 8; ++j){
    int k = kbase + j;
    short o = 0;
    if (k < Ksrc){ o = f2bf(W[(size_t)k * Ncols + n]); }
    v[j] = o;
  }
  *(short8*)(Wp + (size_t)t * 8) = v;
}
__device__ __forceinline__ void pack_w1pq_dev(const float* __restrict__ W1,
                                              short* __restrict__ Wp, int t){
  int lane = t & 63;
  int rest = t >> 6;
  int nt = rest % 32;
  int chunk = rest / 32;
  int col = nt * 16 + (lane & 15);
  int kbase = chunk * 32 + (lane >> 4) * 8;
  short8 v;
  for (int j = 0; j < 8; ++j){
    int k = kbase + j;
    short o = 0;
    if (k < 144){
      float w = (col < 256) ? W1[(size_t)k * 256 + col]
                            : W1[(size_t)(144 + k) * 256 + (col - 256)];
      o = f2bf(w);
    }
    v[j] = o;
  }
  *(short8*)(Wp + (size_t)t * 8) = v;
}

__global__ void pack_hist_kernel(const float* __restrict__ mW1, const float* __restrict__ mW2,
                                 const float* __restrict__ uW1, const float* __restrict__ uW2,
                                 short* __restrict__ w1pq, short* __restrict__ w2m,
                                 short* __restrict__ w1u, short* __restrict__ w2u,
                                 const int* __restrict__ ei, int* __restrict__ cnt){
  int t = blockIdx.x * blockDim.x + threadIdx.x;
  if (t < E_EDGES){
    int tg = ei[E_EDGES + t];
    if ((unsigned)tg >= (unsigned)N_NODES) tg = 0;
    atomicAdd(cnt + tg, 1);
    return;
  }
  int t2 = t - E_EDGES;
  if (t2 >= PACK_THREADS) return;
  if (t2 < 4096){ pack_w_dev(mW2, w2m, 256, 8, t2); }
  else if (t2 < 13312){ pack_w_dev(uW1, w1u, 272, 16, t2 - 4096); }
  else if (t2 < 17408){ pack_w_dev(uW2, w2u, 256, 8, t2 - 13312); }
  else { pack_w1pq_dev(mW1, w1pq, t2 - 17408); }
}

// ---- scans ----
__global__ void scan1_kernel(const int* __restrict__ cnt, int* __restrict__ off,
                             int* __restrict__ bsum){
  __shared__ int sD[256];
  int t = threadIdx.x;
  int g = blockIdx.x * 256 + t;
  int v = cnt[g];
  sD[t] = v;
  __syncthreads();
  for (int d = 1; d < 256; d <<= 1){
    int x2 = (t >= d) ? sD[t - d] : 0;
    __syncthreads();
    sD[t] += x2;
    __syncthreads();
  }
  off[g] = sD[t] - v;
  if (t == 255){ bsum[blockIdx.x] = sD[t]; }
}
__global__ void scan2_kernel(const int* __restrict__ bsum, int* __restrict__ bsumEx){
  __shared__ int sD[256];
  int t = threadIdx.x;
  int v = (t < NBLK_SCAN) ? bsum[t] : 0;
  sD[t] = v;
  __syncthreads();
  for (int d = 1; d < 256; d <<= 1){
    int x2 = (t >= d) ? sD[t - d] : 0;
    __syncthreads();
    sD[t] += x2;
    __syncthreads();
  }
  bsumEx[t] = sD[t] - v;
}

// ---- fused PQ GEMM + edge scatter ----
__launch_bounds__(256, 2)
__global__ void pq_scatter_kernel(const short* __restrict__ h, const short* __restrict__ w1pq,
                                  const float* __restrict__ b1, short* __restrict__ PQ,
                                  const int* __restrict__ ei, int* __restrict__ offA,
                                  const int* __restrict__ bsumEx, unsigned int* __restrict__ es){
  __shared__ short sA[64 * KA_LD];

  if (blockIdx.x >= PQ_BLOCKS){
    int e = (blockIdx.x - PQ_BLOCKS) * 256 + threadIdx.x;
    if (e < E_EDGES){
      int s = ei[e];
      int t = ei[E_EDGES + e];
      if ((unsigned)s >= (unsigned)N_NODES) s = 0;
      if ((unsigned)t >= (unsigned)N_NODES) t = 0;
      int pos = atomicAdd(offA + t, 1) + bsumEx[t >> 8];
      es[pos] = ((unsigned int)t << 16) | (unsigned int)s;
    }
    return;
  }

  const int tid  = threadIdx.x;
  const int lane = tid & 63;
  const int wave = tid >> 6;
  const int q    = lane >> 4;
  const int lr   = lane & 15;
  const int n0   = blockIdx.x * 64;

  {
    int row = tid >> 2;
    int quarter = tid & 3;
    int n = n0 + row;
    if (n >= N_NODES) n = 0;
    const short* hp = h + (size_t)n * DF;
    short* dstp = sA + row * KA_LD + quarter * 40;
    #pragma unroll
    for (int c5 = 0; c5 < 5; ++c5){
      int col = quarter * 40 + c5 * 8;
      short8 v;
      if (col < DF){
        v = *(const short8*)(hp + col);
      } else {
        for (int j = 0; j < 8; ++j){ v[j] = 0; }
      }
      *(short8*)(dstp + c5 * 8) = v;
    }
  }
  __syncthreads();

  floatx4 acc[4][8];
  #pragma unroll
  for (int it = 0; it < 4; ++it){
    #pragma unroll
    for (int jt = 0; jt < 8; ++jt){
      #pragma unroll
      for (int r = 0; r < 4; ++r){ acc[it][jt][r] = 0.0f; }
    }
  }

  for (int kc = 0; kc < 5; ++kc){
    short8 aF[4];
    #pragma unroll
    for (int it = 0; it < 4; ++it){
      aF[it] = *(const short8*)(sA + (it * 16 + lr) * KA_LD + kc * 32 + q * 8);
    }
    #pragma unroll
    for (int jt = 0; jt < 8; ++jt){
      short8 bF = *(const short8*)(w1pq + ((size_t)(kc * 32 + wave * 8 + jt) * 64 + lane) * 8);
      #pragma unroll
      for (int it = 0; it < 4; ++it){
        acc[it][jt] = __builtin_amdgcn_mfma_f32_16x16x32_bf16(aF[it], bF, acc[it][jt], 0, 0, 0);
      }
    }
  }

  #pragma unroll
  for (int jt = 0; jt < 8; ++jt){
    int col  = (wave * 8 + jt) * 16 + lr;
    int colb = (wave * 8 + jt) * 16 + (lr & ~1);
    float bb = (col < 256) ? b1[col] : 0.0f;
    #pragma unroll
    for (int it = 0; it < 4; ++it){
      floatx4 a = acc[it][jt];
      unsigned int pk01 = pk_trunc(a[0] + bb, a[1] + bb);
      unsigned int pk23 = pk_trunc(a[2] + bb, a[3] + bb);
      unsigned int send = (lr & 1) ? pk01 : pk23;
      unsigned int t = (unsigned int)__shfl_xor((int)send, 1, 64);
      int rowbase;
      unsigned int w0, w1;
      if ((lr & 1) == 0){
        rowbase = n0 + it * 16 + q * 4;
        w0 = (pk01 & 0xffffu) | ((t & 0xffffu) << 16);
        w1 = (pk01 >> 16)     | (t & 0xffff0000u);
      } else {
        rowbase = n0 + it * 16 + q * 4 + 2;
        w0 = (t & 0xffffu) | ((pk23 & 0xffffu) << 16);
        w1 = (t >> 16)     | (pk23 & 0xffff0000u);
      }
      if (rowbase < N_NODES){
        *(unsigned int*)(PQ + (size_t)rowbase * PQ_LD + colb) = w0;
      }
      if (rowbase + 1 < N_NODES){
        *(unsigned int*)(PQ + (size_t)(rowbase + 1) * PQ_LD + colb) = w1;
      }
    }
  }
}

// ---- edge3: streaming segmented reduction Hsum[t] += relu(P'[t]+Q[s]) ----
__launch_bounds__(256, 8)
__global__ void edge3_kernel(const short* __restrict__ PQ, const unsigned int* __restrict__ es,
                             float* __restrict__ Hsum){
  const int lane = threadIdx.x & 63;
  const int wave = threadIdx.x >> 6;
  const int wbase = (blockIdx.x * 4 + wave) * 64;
  const unsigned int* PQu = (const unsigned int*)PQ;

  unsigned int myes = es[wbase + lane];
  unsigned int u = (unsigned int)__shfl((int)myes, 0, 64);
  int cur = (int)(u >> 16);

  float Pf0, Pf1, Pf2, Pf3;
  {
    uint2 pv = *(const uint2*)(PQu + (size_t)cur * 256 + lane * 2);
    Pf0 = uasf(pv.x << 16); Pf1 = uasf(pv.x & 0xffff0000u);
    Pf2 = uasf(pv.y << 16); Pf3 = uasf(pv.y & 0xffff0000u);
  }
  float a0 = 0.0f, a1 = 0.0f, a2 = 0.0f, a3 = 0.0f;
  uint2 qv = *(const uint2*)(PQu + (size_t)(u & 0xffffu) * 256 + 128 + lane * 2);

  for (int e = 0; e < 64; ++e){
    unsigned int un = 0u;
    uint2 qn;
    if (e < 63){
      un = (unsigned int)__shfl((int)myes, e + 1, 64);
      qn = *(const uint2*)(PQu + (size_t)(un & 0xffffu) * 256 + 128 + lane * 2);
    }
    int t = (int)(u >> 16);
    if (t != cur){                       // wave-uniform branch
      float* dst = Hsum + (size_t)cur * 256 + lane * 4;
      unsafeAtomicAdd(dst + 0, a0);
      unsafeAtomicAdd(dst + 1, a1);
      unsafeAtomicAdd(dst + 2, a2);
      unsafeAtomicAdd(dst + 3, a3);
      a0 = 0.0f; a1 = 0.0f; a2 = 0.0f; a3 = 0.0f;
      cur = t;
      uint2 pv = *(const uint2*)(PQu + (size_t)cur * 256 + lane * 2);
      Pf0 = uasf(pv.x << 16); Pf1 = uasf(pv.x & 0xffff0000u);
      Pf2 = uasf(pv.y << 16); Pf3 = uasf(pv.y & 0xffff0000u);
    }
    float v;
    v = Pf0 + uasf(qv.x << 16);          a0 += v > 0.0f ? v : 0.0f;
    v = Pf1 + uasf(qv.x & 0xffff0000u);  a1 += v > 0.0f ? v : 0.0f;
    v = Pf2 + uasf(qv.y << 16);          a2 += v > 0.0f ? v : 0.0f;
    v = Pf3 + uasf(qv.y & 0xffff0000u);  a3 += v > 0.0f ? v : 0.0f;
    u = un; qv = qn;
  }
  float* dst = Hsum + (size_t)cur * 256 + lane * 4;
  unsafeAtomicAdd(dst + 0, a0);
  unsafeAtomicAdd(dst + 1, a1);
  unsafeAtomicAdd(dst + 2, a2);
  unsafeAtomicAdd(dst + 3, a3);
}

// ---- node2: agg = Hsum@W2m + cnt*b2m fused in front of the node MLP ----
__launch_bounds__(256, 4)
__global__ void node2_kernel(const short* __restrict__ h, const float* __restrict__ Hsum,
                             const int* __restrict__ cnt,
                             const short* __restrict__ w2m, const float* __restrict__ b2m,
                             const short* __restrict__ w1u, const float* __restrict__ b1u,
                             const short* __restrict__ w2u, const float* __restrict__ b2u,
                             float* __restrict__ out){
  __shared__ __align__(16) short sBuf[64 * SA_LD];
  __shared__ int sCnt[64];
  const int tid  = threadIdx.x;
  const int lane = tid & 63;
  const int wave = tid >> 6;
  const int q    = lane >> 4;
  const int lr   = lane & 15;
  const int n0   = blockIdx.x * 64;

  // Phase A: stage bf16(Hsum) rows (SA_LD stride, cols 0..255) + sCnt
  {
    int row = tid >> 2;
    int qtr = tid & 3;
    int n = n0 + row; if (n >= N_NODES) n = 0;
    const float* hp = Hsum + (size_t)n * 256 + qtr * 64;
    unsigned int* dst = (unsigned int*)(sBuf + row * SA_LD) + qtr * 32;
    #pragma unroll
    for (int i = 0; i < 16; ++i){
      float4 f = *(const float4*)(hp + i * 4);
      dst[i * 2]     = pk_trunc(f.x, f.y);
      dst[i * 2 + 1] = pk_trunc(f.z, f.w);
    }
    if (tid < 64){
      int n2 = n0 + tid; if (n2 >= N_NODES) n2 = 0;
      sCnt[tid] = cnt[n2];
    }
  }
  __syncthreads();

  // Phase B: agg tile = Hsum_bf16 @ W2m
  floatx4 agga[4][2];
  #pragma unroll
  for (int it = 0; it < 4; ++it){
    #pragma unroll
    for (int jt = 0; jt < 2; ++jt){
      #pragma unroll
      for (int r = 0; r < 4; ++r){ agga[it][jt][r] = 0.0f; }
    }
  }
  for (int kc = 0; kc < 8; ++kc){
    short8 aF[4];
    #pragma unroll
    for (int it = 0; it < 4; ++it){
      aF[it] = *(const short8*)(sBuf + (it * 16 + lr) * SA_LD + kc * 32 + q * 8);
    }
    #pragma unroll
    for (int jt = 0; jt < 2; ++jt){
      short8 bF = *(const short8*)(w2m + ((size_t)(kc * 8 + wave * 2 + jt) * 64 + lane) * 8);
      #pragma unroll
      for (int it = 0; it < 4; ++it){
        agga[it][jt] = __builtin_amdgcn_mfma_f32_16x16x32_bf16(aF[it], bF, agga[it][jt], 0, 0, 0);
      }
    }
  }
  __syncthreads();

  // Phase C: restage h (cols 0..143) + pad (272..287) + agg tile (144..271)
  if (tid < 128){
    int row = tid >> 1;
    int half = tid & 1;
    int n = n0 + row; if (n >= N_NODES) n = 0;
    const short* srcp = h + (size_t)n * DF + half * 72;
    short* dstp = sBuf + row * SA_LD + half * 72;
    #pragma unroll
    for (int c = 0; c < 9; ++c){
      *(short8*)(dstp + c * 8) = *(const short8*)(srcp + c * 8);
    }
  } else {
    int t2 = tid - 128;
    int row = t2 >> 1;
    int half = t2 & 1;
    short* padp = sBuf + row * SA_LD + 272 + half * 8;
    #pragma unroll
    for (int t = 0; t < 8; ++t){ padp[t] = 0; }
  }
  #pragma unroll
  for (int jt = 0; jt < 2; ++jt){
    int colm = wave * 32 + jt * 16 + lr;                 // agg col 0..127
    int colb = 144 + wave * 32 + jt * 16 + (lr & ~1);
    float bb = b2m[colm];
    #pragma unroll
    for (int it = 0; it < 4; ++it){
      int rb = it * 16 + q * 4;
      float v0 = agga[it][jt][0] + (float)sCnt[rb + 0] * bb;
      float v1 = agga[it][jt][1] + (float)sCnt[rb + 1] * bb;
      float v2 = agga[it][jt][2] + (float)sCnt[rb + 2] * bb;
      float v3 = agga[it][jt][3] + (float)sCnt[rb + 3] * bb;
      unsigned int pk01 = pk_trunc(v0, v1);
      unsigned int pk23 = pk_trunc(v2, v3);
      unsigned int send = (lr & 1) ? pk01 : pk23;
      unsigned int t = (unsigned int)__shfl_xor((int)send, 1, 64);
      int row0;
      unsigned int w0, w1;
      if ((lr & 1) == 0){
        row0 = rb;
        w0 = (pk01 & 0xffffu) | ((t & 0xffffu) << 16);
        w1 = (pk01 >> 16)     | (t & 0xffff0000u);
      } else {
        row0 = rb + 2;
        w0 = (t & 0xffffu) | ((pk23 & 0xffffu) << 16);
        w1 = (t >> 16)     | (pk23 & 0xffff0000u);
      }
      *(unsigned int*)(sBuf + row0 * SA_LD + colb) = w0;
      *(unsigned int*)(sBuf + (row0 + 1) * SA_LD + colb) = w1;
    }
  }
  __syncthreads();

  // Phase D: layer 1 (K=288) -> relu -> SH_LD hidden
  floatx4 acc[4][4];
  #pragma unroll
  for (int it = 0; it < 4; ++it){
    #pragma unroll
    for (int jt = 0; jt < 4; ++jt){
      #pragma unroll
      for (int r = 0; r < 4; ++r){ acc[it][jt][r] = 0.0f; }
    }
  }
  for (int kc = 0; kc < 9; ++kc){
    short8 aF[4];
    #pragma unroll
    for (int it = 0; it < 4; ++it){
      aF[it] = *(const short8*)(sBuf + (it * 16 + lr) * SA_LD + kc * 32 + q * 8);
    }
    #pragma unroll
    for (int jt = 0; jt < 4; ++jt){
      short8 bF = *(const short8*)(w1u + ((size_t)(kc * 16 + wave * 4 + jt) * 64 + lane) * 8);
      #pragma unroll
      for (int it = 0; it < 4; ++it){
        acc[it][jt] = __builtin_amdgcn_mfma_f32_16x16x32_bf16(aF[it], bF, acc[it][jt], 0, 0, 0);
      }
    }
  }
  __syncthreads();
  #pragma unroll
  for (int jt = 0; jt < 4; ++jt){
    int col  = wave * 64 + jt * 16 + lr;
    int colb = wave * 64 + jt * 16 + (lr & ~1);
    float bb = b1u[col];
    #pragma unroll
    for (int it = 0; it < 4; ++it){
      floatx4 a = acc[it][jt];
      float v0 = a[0] + bb; v0 = v0 > 0.0f ? v0 : 0.0f;
      float v1 = a[1] + bb; v1 = v1 > 0.0f ? v1 : 0.0f;
      float v2 = a[2] + bb; v2 = v2 > 0.0f ? v2 : 0.0f;
      float v3 = a[3] + bb; v3 = v3 > 0.0f ? v3 : 0.0f;
      unsigned int pk01 = pk_trunc(v0, v1);
      unsigned int pk23 = pk_trunc(v2, v3);
      unsigned int send = (lr & 1) ? pk01 : pk23;
      unsigned int t = (unsigned int)__shfl_xor((int)send, 1, 64);
      int row0;
      unsigned int w0, w1;
      if ((lr & 1) == 0){
        row0 = it * 16 + q * 4;
        w0 = (pk01 & 0xffffu) | ((t & 0xffffu) << 16);
        w1 = (pk01 >> 16)     | (t & 0xffff0000u);
      } else {
        row0 = it * 16 + q * 4 + 2;
        w0 = (t & 0xffffu) | ((pk23 & 0xffffu) << 16);
        w1 = (t >> 16)     | (pk23 & 0xffff0000u);
      }
      *(unsigned int*)(sBuf + row0 * SH_LD + colb) = w0;
      *(unsigned int*)(sBuf + (row0 + 1) * SH_LD + colb) = w1;
    }
  }
  __syncthreads();

  // Phase E: layer 2 -> out
  floatx4 acc2[4][2];
  #pragma unroll
  for (int it = 0; it < 4; ++it){
    #pragma unroll
    for (int jt = 0; jt < 2; ++jt){
      #pragma unroll
      for (int r = 0; r < 4; ++r){ acc2[it][jt][r] = 0.0f; }
    }
  }
  for (int kc = 0; kc < 8; ++kc){
    short8 aF[4];
    #pragma unroll
    for (int it = 0; it < 4; ++it){
      aF[it] = *(const short8*)(sBuf + (it * 16 + lr) * SH_LD + kc * 32 + q * 8);
    }
    #pragma unroll
    for (int jt = 0; jt < 2; ++jt){
      short8 bF = *(const short8*)(w2u + ((size_t)(kc * 8 + wave * 2 + jt) * 64 + lane) * 8);
      #pragma unroll
      for (int it = 0; it < 4; ++it){
        acc2[it][jt] = __builtin_amdgcn_mfma_f32_16x16x32_bf16(aF[it], bF, acc2[it][jt], 0, 0, 0);
      }
    }
  }
  #pragma unroll
  for (int jt = 0; jt < 2; ++jt){
    int col = wave * 32 + jt * 16 + lr;
    float bb = b2u[col];
    #pragma unroll
    for (int it = 0; it < 4; ++it){
      #pragma unroll
      for (int r = 0; r < 4; ++r){
        int n = n0 + it * 16 + q * 4 + r;
        if (n < N_NODES){
          out[(size_t)n * DMSG + col] = acc2[it][jt][r] + bb;
        }
      }
    }
  }
}

// ==================== R8 fallback kernels (verified) ====================
__launch_bounds__(256, 4)
__global__ void edge2_kernel(const short* __restrict__ PQ, const unsigned int* __restrict__ es,
                             const short* __restrict__ w2p, const float* __restrict__ b2,
                             float* __restrict__ agg){
  __shared__ __align__(16) short sRaw[64 * SH_LD];
  __shared__ int sTgt[64];
  short* sIn = sRaw;
  float* sMsg = (float*)sRaw;
  const int tid  = threadIdx.x;
  const int lane = tid & 63;
  const int wave = tid >> 6;
  const int q    = lane >> 4;
  const int lr   = lane & 15;
  const int p0   = blockIdx.x * 64;
  {
    int p = tid >> 2;
    int quarter = tid & 3;
    unsigned int e = es[p0 + p];
    int src = (int)(e & 0xffffu);
    int tgt = (int)(e >> 16);
    if (quarter == 0){ sTgt[p] = tgt; }
    const unsigned int* Pp = (const unsigned int*)PQ + (size_t)tgt * 256;
    const unsigned int* Qp = (const unsigned int*)PQ + (size_t)src * 256 + 128;
    unsigned int* sRow = (unsigned int*)(sIn + p * SH_LD);
    #pragma unroll
    for (int i = 0; i < 4; ++i){
      int ub = i * 32 + quarter * 8;
      uint4 pa = *(const uint4*)(Pp + ub);
      uint4 pb = *(const uint4*)(Pp + ub + 4);
      uint4 qa = *(const uint4*)(Qp + ub);
      uint4 qb = *(const uint4*)(Qp + ub + 4);
      uint4 oa, ob;
      oa.x = addrelu_pk(pa.x, qa.x);
      oa.y = addrelu_pk(pa.y, qa.y);
      oa.z = addrelu_pk(pa.z, qa.z);
      oa.w = addrelu_pk(pa.w, qa.w);
      ob.x = addrelu_pk(pb.x, qb.x);
      ob.y = addrelu_pk(pb.y, qb.y);
      ob.z = addrelu_pk(pb.z, qb.z);
      ob.w = addrelu_pk(pb.w, qb.w);
      *(uint4*)(sRow + ub) = oa;
      *(uint4*)(sRow + ub + 4) = ob;
    }
  }
  __syncthreads();
  floatx4 acc2[4][2];
  #pragma unroll
  for (int it = 0; it < 4; ++it){
    #pragma unroll
    for (int jt = 0; jt < 2; ++jt){
      #pragma unroll
      for (int r = 0; r < 4; ++r){ acc2[it][jt][r] = 0.0f; }
    }
  }
  for (int kc = 0; kc < 8; ++kc){
    short8 aF[4];
    #pragma unroll
    for (int it = 0; it < 4; ++it){
      aF[it] = *(const short8*)(sIn + (it * 16 + lr) * SH_LD + kc * 32 + q * 8);
    }
    #pragma unroll
    for (int jt = 0; jt < 2; ++jt){
      short8 bF = *(const short8*)(w2p + ((size_t)(kc * 8 + wave * 2 + jt) * 64 + lane) * 8);
      #pragma unroll
      for (int it = 0; it < 4; ++it){
        acc2[it][jt] = __builtin_amdgcn_mfma_f32_16x16x32_bf16(aF[it], bF, acc2[it][jt], 0, 0, 0);
      }
    }
  }
  __syncthreads();
  #pragma unroll
  for (int jt = 0; jt < 2; ++jt){
    int col = wave * 32 + jt * 16 + lr;
    float bb = b2[col];
    #pragma unroll
    for (int it = 0; it < 4; ++it){
      #pragma unroll
      for (int r = 0; r < 4; ++r){
        sMsg[(it * 16 + q * 4 + r) * MSG_LD + col] = acc2[it][jt][r] + bb;
      }
    }
  }
  __syncthreads();
  {
    int col = tid & 127;
    int r0  = (tid >> 7) * 32;
    float a = 0.0f;
    int cur = sTgt[r0];
    for (int r = r0; r < r0 + 32; ++r){
      int t2 = sTgt[r];
      if (t2 != cur){
        unsafeAtomicAdd(agg + (size_t)cur * DMSG + col, a);
        a = 0.0f;
        cur = t2;
      }
      a += sMsg[r * MSG_LD + col];
    }
    unsafeAtomicAdd(agg + (size_t)cur * DMSG + col, a);
  }
}

__launch_bounds__(256, 4)
__global__ void node_kernel(const short* __restrict__ h, const float* __restrict__ agg,
                            const short* __restrict__ w1p, const short* __restrict__ w2p,
                            const float* __restrict__ b1, const float* __restrict__ b2,
                            float* __restrict__ out){
  __shared__ __align__(16) short sBuf[64 * SA_LD];
  const int tid  = threadIdx.x;
  const int lane = tid & 63;
  const int wave = tid >> 6;
  const int q    = lane >> 4;
  const int lr   = lane & 15;
  const int n0   = blockIdx.x * 64;
  if (tid < 128){
    int row = tid >> 1;
    int half = tid & 1;
    int n = n0 + row;
    if (n >= N_NODES) n = 0;
    const short* srcp = h + (size_t)n * DF + half * 72;
    short* dstp = sBuf + row * SA_LD + half * 72;
    #pragma unroll
    for (int c = 0; c < 9; ++c){
      *(short8*)(dstp + c * 8) = *(const short8*)(srcp + c * 8);
    }
  } else {
    int t2 = tid - 128;
    int row = t2 >> 1;
    int half = t2 & 1;
    int n = n0 + row;
    if (n >= N_NODES) n = 0;
    const float* ap = agg + (size_t)n * DMSG + half * 64;
    unsigned int* dstp = (unsigned int*)(sBuf + row * SA_LD + DF + half * 64);
    #pragma unroll
    for (int c = 0; c < 16; ++c){
      float4 f = *(const float4*)(ap + c * 4);
      dstp[c * 2]     = pk_trunc(f.x, f.y);
      dstp[c * 2 + 1] = pk_trunc(f.z, f.w);
    }
    short* padp = sBuf + row * SA_LD + 272 + half * 8;
    #pragma unroll
    for (int t = 0; t < 8; ++t){ padp[t] = 0; }
  }
  __syncthreads();
  floatx4 acc[4][4];
  #pragma unroll
  for (int it = 0; it < 4; ++it){
    #pragma unroll
    for (int jt = 0; jt < 4; ++jt){
      #pragma unroll
      for (int r = 0; r < 4; ++r){ acc[it][jt][r] = 0.0f; }
    }
  }
  for (int kc = 0; kc < 9; ++kc){
    short8 aF[4];
    #pragma unroll
    for (int it = 0; it < 4; ++it){
      aF[it] = *(const short8*)(sBuf + (it * 16 + lr) * SA_LD + kc * 32 + q * 8);
    }
    #pragma unroll
    for (int jt = 0; jt < 4; ++jt){
      short8 bF = *(const short8*)(w1p + ((size_t)(kc * 16 + wave * 4 + jt) * 64 + lane) * 8);
      #pragma unroll
      for (int it = 0; it < 4; ++it){
        acc[it][jt] = __builtin_amdgcn_mfma_f32_16x16x32_bf16(aF[it], bF, acc[it][jt], 0, 0, 0);
      }
    }
  }
  __syncthreads();
  #pragma unroll
  for (int jt = 0; jt < 4; ++jt){
    int col  = wave * 64 + jt * 16 + lr;
    int colb = wave * 64 + jt * 16 + (lr & ~1);
    float bb = b1[col];
    #pragma unroll
    for (int it = 0; it < 4; ++it){
      floatx4 a = acc[it][jt];
      float v0 = a[0] + bb; v0 = v0 > 0.0f ? v0 : 0.0f;
      float v1 = a[1] + bb; v1 = v1 > 0.0f ? v1 : 0.0f;
      float v2 = a[2] + bb; v2 = v2 > 0.0f ? v2 : 0.0f;
      float v3 = a[3] + bb; v3 = v3 > 0.0f ? v3 : 0.0f;
      unsigned int pk01 = pk_trunc(v0, v1);
      unsigned int pk23 = pk_trunc(v2, v3);
      unsigned int send = (lr & 1) ? pk01 : pk23;
      unsigned int t = (unsigned int)__shfl_xor((int)send, 1, 64);
      int row0;
      unsigned int w0, w1;
      if ((lr & 1) == 0){
        row0 = it * 16 + q * 4;
        w0 = (pk01 & 0xffffu) | ((t & 0xffffu) << 16);
        w1 = (pk01 >> 16)     | (t & 0xffff0000u);
      } else {
        row0 = it * 16 + q * 4 + 2;
        w0 = (t & 0xffffu) | ((pk23 & 0xffffu) << 16);
        w1 = (t >> 16)     | (pk23 & 0xffff0000u);
      }
      *(unsigned int*)(sBuf + row0 * SH_LD + colb) = w0;
      *(unsigned int*)(sBuf + (row0 + 1) * SH_LD + colb) = w1;
    }
  }
  __syncthreads();
  floatx4 acc2[4][2];
  #pragma unroll
  for (int it = 0; it < 4; ++it){
    #pragma unroll
    for (int jt = 0; jt < 2; ++jt){
      #pragma unroll
      for (int r = 0; r < 4; ++r){ acc2[it][jt][r] = 0.0f; }
    }
  }
  for (int kc = 0; kc < 8; ++kc){
    short8 aF[4];
    #pragma unroll
    for (int it = 0; it < 4; ++it){
      aF[it] = *(const short8*)(sBuf + (it * 16 + lr) * SH_LD + kc * 32 + q * 8);
    }
    #pragma unroll
    for (int jt = 0; jt < 2; ++jt){
      short8 bF = *(const short8*)(w2p + ((size_t)(kc * 8 + wave * 2 + jt) * 64 + lane) * 8);
      #pragma unroll
      for (int it = 0; it < 4; ++it){
        acc2[it][jt] = __builtin_amdgcn_mfma_f32_16x16x32_bf16(aF[it], bF, acc2[it][jt], 0, 0, 0);
      }
    }
  }
  #pragma unroll
  for (int jt = 0; jt < 2; ++jt){
    int col = wave * 32 + jt * 16 + lr;
    float bb = b2[col];
    #pragma unroll
    for (int it = 0; it < 4; ++it){
      #pragma unroll
      for (int r = 0; r < 4; ++r){
        int n = n0 + it * 16 + q * 4 + r;
        if (n < N_NODES){
          out[(size_t)n * DMSG + col] = acc2[it][jt][r] + bb;
        }
      }
    }
  }
}

extern "C" void kernel_launch(void* const* d_in, const int* in_sizes, int n_in,
                              void* d_out, int out_size, void* d_ws, size_t ws_size,
                              hipStream_t stream){
  const float* x   = (const float*)d_in[0];
  const int*   ei  = (const int*)d_in[1];
  const float* deg = (const float*)d_in[2];
  const float* mW1 = (const float*)d_in[3];
  const float* mb1 = (const float*)d_in[4];
  const float* mW2 = (const float*)d_in[5];
  const float* mb2 = (const float*)d_in[6];
  const float* uW1 = (const float*)d_in[7];
  const float* ub1 = (const float*)d_in[8];
  const float* uW2 = (const float*)d_in[9];
  const float* ub2 = (const float*)d_in[10];

  const size_t fixed = (size_t)N_NODES * DF * 2 + 512 +
                       (size_t)(4096 + 9216 + 4096 + 10240) * 64 +
                       512 + (size_t)N_NODES * PQ_LD * 2 + (size_t)E_EDGES * 4 +
                       (size_t)NSCAN * 8 + 2048;
  const size_t need_new = fixed + (size_t)N_NODES * 256 * 4;   // Hsum 51.2 MB
  const size_t need_old = fixed + (size_t)N_NODES * DMSG * 4;  // agg  25.6 MB
  bool big = (ws_size >= need_new);

  char* ws = (char*)d_ws;
  size_t off = 0;
  float* Hsum = (float*)(ws + off);                 // new path (or agg, old path)
  float* agg  = Hsum;
  off += big ? (size_t)N_NODES * 256 * 4 : (size_t)N_NODES * DMSG * 4;
  short* hbuf = (short*)(ws + off); off += (size_t)N_NODES * DF * 2;
  off = (off + 255) & ~(size_t)255;
  short* w2m = (short*)(ws + off); off += (size_t)8 * 8 * 64 * 8 * 2;
  short* w1u = (short*)(ws + off); off += (size_t)9 * 16 * 64 * 8 * 2;
  short* w2u = (short*)(ws + off); off += (size_t)8 * 8 * 64 * 8 * 2;
  short* w1pq = (short*)(ws + off); off += (size_t)5 * 32 * 64 * 8 * 2;
  off = (off + 255) & ~(size_t)255;
  short* PQ = (short*)(ws + off); off += (size_t)N_NODES * PQ_LD * 2;
  unsigned int* es = (unsigned int*)(ws + off); off += (size_t)E_EDGES * 4;
  int* cnt    = (int*)(ws + off); off += (size_t)NSCAN * 4;
  int* offA   = (int*)(ws + off); off += (size_t)NSCAN * 4;
  int* bsum   = (int*)(ws + off); off += 256 * 4;
  int* bsumEx = (int*)(ws + off); off += 256 * 4;

  if (ws_size < off){
    sentinel_kernel<<<(N_NODES * DMSG + 255) / 256, 256, 0, stream>>>((float*)d_out);
    return;
  }

  int nzf4 = big ? (N_NODES * 256 / 4) : (N_NODES * DMSG / 4);
  int pthreads = nzf4 > N_NODES * 18 ? nzf4 : N_NODES * 18;
  prep_kernel<<<(pthreads + 255) / 256, 256, 0, stream>>>(x, deg, (float4*)Hsum, nzf4,
                                                          cnt, hbuf);
  pack_hist_kernel<<<HIST_BLOCKS + PACK_THREADS / 256, 256, 0, stream>>>(
      mW1, mW2, uW1, uW2, w1pq, w2m, w1u, w2u, ei, cnt);
  scan1_kernel<<<NBLK_SCAN, 256, 0, stream>>>(cnt, offA, bsum);
  scan2_kernel<<<1, 256, 0, stream>>>(bsum, bsumEx);
  pq_scatter_kernel<<<PQ_BLOCKS + HIST_BLOCKS, 256, 0, stream>>>(
      hbuf, w1pq, mb1, PQ, ei, offA, bsumEx, es);

  if (big){
    edge3_kernel<<<E_EDGES / 256, 256, 0, stream>>>(PQ, es, Hsum);
    node2_kernel<<<(N_NODES + 63) / 64, 256, 0, stream>>>(hbuf, Hsum, cnt, w2m, mb2,
                                                          w1u, ub1, w2u, ub2,
                                                          (float*)d_out);
  } else {
    edge2_kernel<<<E_EDGES / 64, 256, 0, stream>>>(PQ, es, w2m, mb2, agg);
    node_kernel<<<(N_NODES + 63) / 64, 256, 0, stream>>>(hbuf, agg, w1u, w2u, ub1, ub2,
                                                         (float*)d_out);
  }
}

// Round 10
// 326.976 us; speedup vs baseline: 1.4835x; 1.4835x over previous
//
#include <hip/hip_runtime.h>

// MPNN sparse on MI355X (fp32 I/O, bf16 MFMA compute).
// R10: atomic-free edge stage.
//   R9 post-mortem: per-lane 16B-strided atomic flushes -> 4x HBM write
//   amplification (247 MB measured) -> memory-side RMW wall. Fix: edges are
//   target-sorted with known segment bounds, so ONE WAVE PER TARGET sums its
//   whole segment and emits Hsum[t] with a single plain coalesced bf16 store.
//   Zero atomics in the hot path. Hsum bf16 also halves node2 staging reads
//   and deletes the 51 MB zero-init from prep.
// Pipeline: prep(cnt=0,h=bf16[x|deg]) -> pack+hist -> scan1 -> scan2 ->
//   pq_scatter (PQ=[hW1a+b1 | hW1b] GEMM + target-sort scatter) ->
//   hsum (per-target segmented sum) -> node2 (Hsum@W2m+cnt*b2m fused MLP).

#define N_NODES 50000
#define E_EDGES 800000
#define DF   144
#define DIN  128
#define DDEG 16
#define DMSG 128
#define SA_LD 296     // 288 + 8 pad (shorts)
#define SH_LD 264     // 256 + 8 pad (shorts)
#define PQ_LD 512     // P'(256) | Q(256) per node, bf16
#define KA_LD 168     // 160 + 8 pad (pq A staging)
#define NSCAN 50176   // 196 * 256
#define NBLK_SCAN 196
#define PQ_BLOCKS 782     // ceil(50000/64)
#define HIST_BLOCKS 3125  // 800000/256
#define PACK_THREADS 27648

typedef __attribute__((ext_vector_type(8))) short short8;
typedef __attribute__((ext_vector_type(4))) float floatx4;

__device__ __forceinline__ unsigned int fasu(float f){
  union { float f; unsigned int u; } v; v.f = f; return v.u;
}
__device__ __forceinline__ float uasf(unsigned int u){
  union { unsigned int u; float f; } v; v.u = u; return v.f;
}
__device__ __forceinline__ short f2bf(float f){           // RNE
  unsigned int i = fasu(f);
  unsigned int r = i + 0x7fffu + ((i >> 16) & 1u);
  return (short)(r >> 16);
}
__device__ __forceinline__ unsigned int pk_trunc(float lo, float hi){
  return __builtin_amdgcn_perm(fasu(hi), fasu(lo), 0x07060302u);
}

// ---- sentinel: ws too small -> out = 2.0 (diagnostic) ----
__global__ void sentinel_kernel(float* __restrict__ out){
  int i = blockIdx.x * blockDim.x + threadIdx.x;
  if (i < N_NODES * DMSG){ out[i] = 2.0f; }
}

// ---- prep: cnt=0, h=bf16([x|deg]) ----
__global__ void prep_kernel(const float* __restrict__ x, const float* __restrict__ deg,
                            int* __restrict__ cnt, short* __restrict__ h){
  int i = blockIdx.x * blockDim.x + threadIdx.x;
  if (i < NSCAN){ cnt[i] = 0; }
  if (i < N_NODES * 18){
    int n = i / 18;
    int j = i - n * 18;
    const float* src;
    if (j < 16){ src = x + (size_t)n * DIN + (size_t)j * 8; }
    else       { src = deg + (size_t)n * DDEG + (size_t)(j - 16) * 8; }
    short8 v;
    for (int t = 0; t < 8; ++t){ v[t] = f2bf(src[t]); }
    *(short8*)(h + (size_t)n * DF + (size_t)j * 8) = v;
  }
}

// ---- pack helpers ----
__device__ __forceinline__ void pack_w_dev(const float* __restrict__ W,
                                           short* __restrict__ Wp,
                                           int Ksrc, int nT, int t){
  int lane = t & 63;
  int rest = t >> 6;
  int nt = rest % nT;
  int chunk = rest / nT;
  int Ncols = nT * 16;
  int n = nt * 16 + (lane & 15);
  int kbase = chunk * 32 + (lane >> 4) * 8;
  short8 v;
  for (int j = 0; j < 8; ++j){
    int k = kbase + j;
    short o = 0;
    if (k < Ksrc){ o = f2bf(W[(size_t)k * Ncols + n]); }
    v[j] = o;
  }
  *(short8*)(Wp + (size_t)t * 8) = v;
}
__device__ __forceinline__ void pack_w1pq_dev(const float* __restrict__ W1,
                                              short* __restrict__ Wp, int t){
  int lane = t & 63;
  int rest = t >> 6;
  int nt = rest % 32;
  int chunk = rest / 32;
  int col = nt * 16 + (lane & 15);
  int kbase = chunk * 32 + (lane >> 4) * 8;
  short8 v;
  for (int j = 0; j < 8; ++j){
    int k = kbase + j;
    short o = 0;
    if (k < 144){
      float w = (col < 256) ? W1[(size_t)k * 256 + col]
                            : W1[(size_t)(144 + k) * 256 + (col - 256)];
      o = f2bf(w);
    }
    v[j] = o;
  }
  *(short8*)(Wp + (size_t)t * 8) = v;
}

__global__ void pack_hist_kernel(const float* __restrict__ mW1, const float* __restrict__ mW2,
                                 const float* __restrict__ uW1, const float* __restrict__ uW2,
                                 short* __restrict__ w1pq, short* __restrict__ w2m,
                                 short* __restrict__ w1u, short* __restrict__ w2u,
                                 const int* __restrict__ ei, int* __restrict__ cnt){
  int t = blockIdx.x * blockDim.x + threadIdx.x;
  if (t < E_EDGES){
    int tg = ei[E_EDGES + t];
    if ((unsigned)tg >= (unsigned)N_NODES) tg = 0;
    atomicAdd(cnt + tg, 1);
    return;
  }
  int t2 = t - E_EDGES;
  if (t2 >= PACK_THREADS) return;
  if (t2 < 4096){ pack_w_dev(mW2, w2m, 256, 8, t2); }
  else if (t2 < 13312){ pack_w_dev(uW1, w1u, 272, 16, t2 - 4096); }
  else if (t2 < 17408){ pack_w_dev(uW2, w2u, 256, 8, t2 - 13312); }
  else { pack_w1pq_dev(mW1, w1pq, t2 - 17408); }
}

// ---- scans ----
__global__ void scan1_kernel(const int* __restrict__ cnt, int* __restrict__ off,
                             int* __restrict__ bsum){
  __shared__ int sD[256];
  int t = threadIdx.x;
  int g = blockIdx.x * 256 + t;
  int v = cnt[g];
  sD[t] = v;
  __syncthreads();
  for (int d = 1; d < 256; d <<= 1){
    int x2 = (t >= d) ? sD[t - d] : 0;
    __syncthreads();
    sD[t] += x2;
    __syncthreads();
  }
  off[g] = sD[t] - v;
  if (t == 255){ bsum[blockIdx.x] = sD[t]; }
}
__global__ void scan2_kernel(const int* __restrict__ bsum, int* __restrict__ bsumEx){
  __shared__ int sD[256];
  int t = threadIdx.x;
  int v = (t < NBLK_SCAN) ? bsum[t] : 0;
  sD[t] = v;
  __syncthreads();
  for (int d = 1; d < 256; d <<= 1){
    int x2 = (t >= d) ? sD[t - d] : 0;
    __syncthreads();
    sD[t] += x2;
    __syncthreads();
  }
  bsumEx[t] = sD[t] - v;
}

// ---- fused PQ GEMM + edge scatter ----
__launch_bounds__(256, 2)
__global__ void pq_scatter_kernel(const short* __restrict__ h, const short* __restrict__ w1pq,
                                  const float* __restrict__ b1, short* __restrict__ PQ,
                                  const int* __restrict__ ei, int* __restrict__ offA,
                                  const int* __restrict__ bsumEx, unsigned int* __restrict__ es){
  __shared__ short sA[64 * KA_LD];

  if (blockIdx.x >= PQ_BLOCKS){
    int e = (blockIdx.x - PQ_BLOCKS) * 256 + threadIdx.x;
    if (e < E_EDGES){
      int s = ei[e];
      int t = ei[E_EDGES + e];
      if ((unsigned)s >= (unsigned)N_NODES) s = 0;
      if ((unsigned)t >= (unsigned)N_NODES) t = 0;
      int pos = atomicAdd(offA + t, 1) + bsumEx[t >> 8];
      es[pos] = ((unsigned int)t << 16) | (unsigned int)s;
    }
    return;
  }

  const int tid  = threadIdx.x;
  const int lane = tid & 63;
  const int wave = tid >> 6;
  const int q    = lane >> 4;
  const int lr   = lane & 15;
  const int n0   = blockIdx.x * 64;

  {
    int row = tid >> 2;
    int quarter = tid & 3;
    int n = n0 + row;
    if (n >= N_NODES) n = 0;
    const short* hp = h + (size_t)n * DF;
    short* dstp = sA + row * KA_LD + quarter * 40;
    #pragma unroll
    for (int c5 = 0; c5 < 5; ++c5){
      int col = quarter * 40 + c5 * 8;
      short8 v;
      if (col < DF){
        v = *(const short8*)(hp + col);
      } else {
        for (int j = 0; j < 8; ++j){ v[j] = 0; }
      }
      *(short8*)(dstp + c5 * 8) = v;
    }
  }
  __syncthreads();

  floatx4 acc[4][8];
  #pragma unroll
  for (int it = 0; it < 4; ++it){
    #pragma unroll
    for (int jt = 0; jt < 8; ++jt){
      #pragma unroll
      for (int r = 0; r < 4; ++r){ acc[it][jt][r] = 0.0f; }
    }
  }

  for (int kc = 0; kc < 5; ++kc){
    short8 aF[4];
    #pragma unroll
    for (int it = 0; it < 4; ++it){
      aF[it] = *(const short8*)(sA + (it * 16 + lr) * KA_LD + kc * 32 + q * 8);
    }
    #pragma unroll
    for (int jt = 0; jt < 8; ++jt){
      short8 bF = *(const short8*)(w1pq + ((size_t)(kc * 32 + wave * 8 + jt) * 64 + lane) * 8);
      #pragma unroll
      for (int it = 0; it < 4; ++it){
        acc[it][jt] = __builtin_amdgcn_mfma_f32_16x16x32_bf16(aF[it], bF, acc[it][jt], 0, 0, 0);
      }
    }
  }

  #pragma unroll
  for (int jt = 0; jt < 8; ++jt){
    int col  = (wave * 8 + jt) * 16 + lr;
    int colb = (wave * 8 + jt) * 16 + (lr & ~1);
    float bb = (col < 256) ? b1[col] : 0.0f;
    #pragma unroll
    for (int it = 0; it < 4; ++it){
      floatx4 a = acc[it][jt];
      unsigned int pk01 = pk_trunc(a[0] + bb, a[1] + bb);
      unsigned int pk23 = pk_trunc(a[2] + bb, a[3] + bb);
      unsigned int send = (lr & 1) ? pk01 : pk23;
      unsigned int t = (unsigned int)__shfl_xor((int)send, 1, 64);
      int rowbase;
      unsigned int w0, w1;
      if ((lr & 1) == 0){
        rowbase = n0 + it * 16 + q * 4;
        w0 = (pk01 & 0xffffu) | ((t & 0xffffu) << 16);
        w1 = (pk01 >> 16)     | (t & 0xffff0000u);
      } else {
        rowbase = n0 + it * 16 + q * 4 + 2;
        w0 = (t & 0xffffu) | ((pk23 & 0xffffu) << 16);
        w1 = (t >> 16)     | (pk23 & 0xffff0000u);
      }
      if (rowbase < N_NODES){
        *(unsigned int*)(PQ + (size_t)rowbase * PQ_LD + colb) = w0;
      }
      if (rowbase + 1 < N_NODES){
        *(unsigned int*)(PQ + (size_t)(rowbase + 1) * PQ_LD + colb) = w1;
      }
    }
  }
}

// ---- hsum: one wave per target; plain coalesced bf16 store, NO atomics ----
__launch_bounds__(256, 8)
__global__ void hsum_kernel(const short* __restrict__ PQ, const unsigned int* __restrict__ es,
                            const int* __restrict__ cnt, const int* __restrict__ offA,
                            const int* __restrict__ bsumEx, short* __restrict__ HsumB){
  const int lane = threadIdx.x & 63;
  const int wave = threadIdx.x >> 6;
  const int t = blockIdx.x * 4 + wave;          // grid covers exactly N_NODES
  const unsigned int* PQu = (const unsigned int*)PQ;

  float a0 = 0.0f, a1 = 0.0f, a2 = 0.0f, a3 = 0.0f;
  int d = cnt[t];
  if (d > 0){
    int start = offA[t] - d + bsumEx[t >> 8];   // offA was mutated to local-end by scatter
    uint2 pv = *(const uint2*)(PQu + (size_t)t * 256 + lane * 2);
    float Pf0 = uasf(pv.x << 16), Pf1 = uasf(pv.x & 0xffff0000u);
    float Pf2 = uasf(pv.y << 16), Pf3 = uasf(pv.y & 0xffff0000u);
    for (int base = 0; base < d; base += 64){
      int m = d - base;
      if (m > 64) m = 64;
      unsigned int el = (lane < m) ? es[start + base + lane] : 0u;
      unsigned int s0 = (unsigned int)__shfl((int)el, 0, 64) & 0xffffu;
      uint2 qv = *(const uint2*)(PQu + (size_t)s0 * 256 + 128 + lane * 2);
      for (int j = 0; j < m; ++j){
        uint2 qn;
        if (j + 1 < m){
          unsigned int s1 = (unsigned int)__shfl((int)el, j + 1, 64) & 0xffffu;
          qn = *(const uint2*)(PQu + (size_t)s1 * 256 + 128 + lane * 2);
        }
        float v;
        v = Pf0 + uasf(qv.x << 16);          a0 += v > 0.0f ? v : 0.0f;
        v = Pf1 + uasf(qv.x & 0xffff0000u);  a1 += v > 0.0f ? v : 0.0f;
        v = Pf2 + uasf(qv.y << 16);          a2 += v > 0.0f ? v : 0.0f;
        v = Pf3 + uasf(qv.y & 0xffff0000u);  a3 += v > 0.0f ? v : 0.0f;
        qv = qn;
      }
    }
  }
  uint2 o;
  o.x = pk_trunc(a0, a1);
  o.y = pk_trunc(a2, a3);
  *(uint2*)((unsigned int*)HsumB + (size_t)t * 128 + lane * 2) = o;
}

// ---- node2: agg = HsumB@W2m + cnt*b2m fused in front of the node MLP ----
__launch_bounds__(256, 4)
__global__ void node2_kernel(const short* __restrict__ h, const short* __restrict__ HsumB,
                             const int* __restrict__ cnt,
                             const short* __restrict__ w2m, const float* __restrict__ b2m,
                             const short* __restrict__ w1u, const float* __restrict__ b1u,
                             const short* __restrict__ w2u, const float* __restrict__ b2u,
                             float* __restrict__ out){
  __shared__ __align__(16) short sBuf[64 * SA_LD];
  __shared__ int sCnt[64];
  const int tid  = threadIdx.x;
  const int lane = tid & 63;
  const int wave = tid >> 6;
  const int q    = lane >> 4;
  const int lr   = lane & 15;
  const int n0   = blockIdx.x * 64;

  // Phase A: stage HsumB rows (bf16 copy, SA_LD stride) + sCnt
  {
    int row = tid >> 2;
    int qtr = tid & 3;
    int n = n0 + row; if (n >= N_NODES) n = 0;
    const short* hp = HsumB + (size_t)n * 256 + qtr * 64;
    short* dst = sBuf + row * SA_LD + qtr * 64;
    #pragma unroll
    for (int c = 0; c < 8; ++c){
      *(short8*)(dst + c * 8) = *(const short8*)(hp + c * 8);
    }
    if (tid < 64){
      int n2 = n0 + tid; if (n2 >= N_NODES) n2 = 0;
      sCnt[tid] = cnt[n2];
    }
  }
  __syncthreads();

  // Phase B: agg tile = Hsum @ W2m
  floatx4 agga[4][2];
  #pragma unroll
  for (int it = 0; it < 4; ++it){
    #pragma unroll
    for (int jt = 0; jt < 2; ++jt){
      #pragma unroll
      for (int r = 0; r < 4; ++r){ agga[it][jt][r] = 0.0f; }
    }
  }
  for (int kc = 0; kc < 8; ++kc){
    short8 aF[4];
    #pragma unroll
    for (int it = 0; it < 4; ++it){
      aF[it] = *(const short8*)(sBuf + (it * 16 + lr) * SA_LD + kc * 32 + q * 8);
    }
    #pragma unroll
    for (int jt = 0; jt < 2; ++jt){
      short8 bF = *(const short8*)(w2m + ((size_t)(kc * 8 + wave * 2 + jt) * 64 + lane) * 8);
      #pragma unroll
      for (int it = 0; it < 4; ++it){
        agga[it][jt] = __builtin_amdgcn_mfma_f32_16x16x32_bf16(aF[it], bF, agga[it][jt], 0, 0, 0);
      }
    }
  }
  __syncthreads();

  // Phase C: restage h (0..143) + pad (272..287) + agg tile (144..271)
  if (tid < 128){
    int row = tid >> 1;
    int half = tid & 1;
    int n = n0 + row; if (n >= N_NODES) n = 0;
    const short* srcp = h + (size_t)n * DF + half * 72;
    short* dstp = sBuf + row * SA_LD + half * 72;
    #pragma unroll
    for (int c = 0; c < 9; ++c){
      *(short8*)(dstp + c * 8) = *(const short8*)(srcp + c * 8);
    }
  } else {
    int t2 = tid - 128;
    int row = t2 >> 1;
    int half = t2 & 1;
    short* padp = sBuf + row * SA_LD + 272 + half * 8;
    #pragma unroll
    for (int t = 0; t < 8; ++t){ padp[t] = 0; }
  }
  #pragma unroll
  for (int jt = 0; jt < 2; ++jt){
    int colm = wave * 32 + jt * 16 + lr;
    int colb = 144 + wave * 32 + jt * 16 + (lr & ~1);
    float bb = b2m[colm];
    #pragma unroll
    for (int it = 0; it < 4; ++it){
      int rb = it * 16 + q * 4;
      float v0 = agga[it][jt][0] + (float)sCnt[rb + 0] * bb;
      float v1 = agga[it][jt][1] + (float)sCnt[rb + 1] * bb;
      float v2 = agga[it][jt][2] + (float)sCnt[rb + 2] * bb;
      float v3 = agga[it][jt][3] + (float)sCnt[rb + 3] * bb;
      unsigned int pk01 = pk_trunc(v0, v1);
      unsigned int pk23 = pk_trunc(v2, v3);
      unsigned int send = (lr & 1) ? pk01 : pk23;
      unsigned int t = (unsigned int)__shfl_xor((int)send, 1, 64);
      int row0;
      unsigned int w0, w1;
      if ((lr & 1) == 0){
        row0 = rb;
        w0 = (pk01 & 0xffffu) | ((t & 0xffffu) << 16);
        w1 = (pk01 >> 16)     | (t & 0xffff0000u);
      } else {
        row0 = rb + 2;
        w0 = (t & 0xffffu) | ((pk23 & 0xffffu) << 16);
        w1 = (t >> 16)     | (pk23 & 0xffff0000u);
      }
      *(unsigned int*)(sBuf + row0 * SA_LD + colb) = w0;
      *(unsigned int*)(sBuf + (row0 + 1) * SA_LD + colb) = w1;
    }
  }
  __syncthreads();

  // Phase D: layer 1 (K=288) -> relu -> SH_LD hidden
  floatx4 acc[4][4];
  #pragma unroll
  for (int it = 0; it < 4; ++it){
    #pragma unroll
    for (int jt = 0; jt < 4; ++jt){
      #pragma unroll
      for (int r = 0; r < 4; ++r){ acc[it][jt][r] = 0.0f; }
    }
  }
  for (int kc = 0; kc < 9; ++kc){
    short8 aF[4];
    #pragma unroll
    for (int it = 0; it < 4; ++it){
      aF[it] = *(const short8*)(sBuf + (it * 16 + lr) * SA_LD + kc * 32 + q * 8);
    }
    #pragma unroll
    for (int jt = 0; jt < 4; ++jt){
      short8 bF = *(const short8*)(w1u + ((size_t)(kc * 16 + wave * 4 + jt) * 64 + lane) * 8);
      #pragma unroll
      for (int it = 0; it < 4; ++it){
        acc[it][jt] = __builtin_amdgcn_mfma_f32_16x16x32_bf16(aF[it], bF, acc[it][jt], 0, 0, 0);
      }
    }
  }
  __syncthreads();
  #pragma unroll
  for (int jt = 0; jt < 4; ++jt){
    int col  = wave * 64 + jt * 16 + lr;
    int colb = wave * 64 + jt * 16 + (lr & ~1);
    float bb = b1u[col];
    #pragma unroll
    for (int it = 0; it < 4; ++it){
      floatx4 a = acc[it][jt];
      float v0 = a[0] + bb; v0 = v0 > 0.0f ? v0 : 0.0f;
      float v1 = a[1] + bb; v1 = v1 > 0.0f ? v1 : 0.0f;
      float v2 = a[2] + bb; v2 = v2 > 0.0f ? v2 : 0.0f;
      float v3 = a[3] + bb; v3 = v3 > 0.0f ? v3 : 0.0f;
      unsigned int pk01 = pk_trunc(v0, v1);
      unsigned int pk23 = pk_trunc(v2, v3);
      unsigned int send = (lr & 1) ? pk01 : pk23;
      unsigned int t = (unsigned int)__shfl_xor((int)send, 1, 64);
      int row0;
      unsigned int w0, w1;
      if ((lr & 1) == 0){
        row0 = it * 16 + q * 4;
        w0 = (pk01 & 0xffffu) | ((t & 0xffffu) << 16);
        w1 = (pk01 >> 16)     | (t & 0xffff0000u);
      } else {
        row0 = it * 16 + q * 4 + 2;
        w0 = (t & 0xffffu) | ((pk23 & 0xffffu) << 16);
        w1 = (t >> 16)     | (pk23 & 0xffff0000u);
      }
      *(unsigned int*)(sBuf + row0 * SH_LD + colb) = w0;
      *(unsigned int*)(sBuf + (row0 + 1) * SH_LD + colb) = w1;
    }
  }
  __syncthreads();

  // Phase E: layer 2 -> out
  floatx4 acc2[4][2];
  #pragma unroll
  for (int it = 0; it < 4; ++it){
    #pragma unroll
    for (int jt = 0; jt < 2; ++jt){
      #pragma unroll
      for (int r = 0; r < 4; ++r){ acc2[it][jt][r] = 0.0f; }
    }
  }
  for (int kc = 0; kc < 8; ++kc){
    short8 aF[4];
    #pragma unroll
    for (int it = 0; it < 4; ++it){
      aF[it] = *(const short8*)(sBuf + (it * 16 + lr) * SH_LD + kc * 32 + q * 8);
    }
    #pragma unroll
    for (int jt = 0; jt < 2; ++jt){
      short8 bF = *(const short8*)(w2u + ((size_t)(kc * 8 + wave * 2 + jt) * 64 + lane) * 8);
      #pragma unroll
      for (int it = 0; it < 4; ++it){
        acc2[it][jt] = __builtin_amdgcn_mfma_f32_16x16x32_bf16(aF[it], bF, acc2[it][jt], 0, 0, 0);
      }
    }
  }
  #pragma unroll
  for (int jt = 0; jt < 2; ++jt){
    int col = wave * 32 + jt * 16 + lr;
    float bb = b2u[col];
    #pragma unroll
    for (int it = 0; it < 4; ++it){
      #pragma unroll
      for (int r = 0; r < 4; ++r){
        int n = n0 + it * 16 + q * 4 + r;
        if (n < N_NODES){
          out[(size_t)n * DMSG + col] = acc2[it][jt][r] + bb;
        }
      }
    }
  }
}

extern "C" void kernel_launch(void* const* d_in, const int* in_sizes, int n_in,
                              void* d_out, int out_size, void* d_ws, size_t ws_size,
                              hipStream_t stream){
  const float* x   = (const float*)d_in[0];
  const int*   ei  = (const int*)d_in[1];
  const float* deg = (const float*)d_in[2];
  const float* mW1 = (const float*)d_in[3];
  const float* mb1 = (const float*)d_in[4];
  const float* mW2 = (const float*)d_in[5];
  const float* mb2 = (const float*)d_in[6];
  const float* uW1 = (const float*)d_in[7];
  const float* ub1 = (const float*)d_in[8];
  const float* uW2 = (const float*)d_in[9];
  const float* ub2 = (const float*)d_in[10];

  char* ws = (char*)d_ws;
  size_t off = 0;
  short* HsumB = (short*)(ws + off); off += (size_t)N_NODES * 256 * 2;   // 25.6 MB
  short* hbuf  = (short*)(ws + off); off += (size_t)N_NODES * DF * 2;    // 14.4 MB
  off = (off + 255) & ~(size_t)255;
  short* w2m  = (short*)(ws + off); off += (size_t)8 * 8 * 64 * 8 * 2;
  short* w1u  = (short*)(ws + off); off += (size_t)9 * 16 * 64 * 8 * 2;
  short* w2u  = (short*)(ws + off); off += (size_t)8 * 8 * 64 * 8 * 2;
  short* w1pq = (short*)(ws + off); off += (size_t)5 * 32 * 64 * 8 * 2;
  off = (off + 255) & ~(size_t)255;
  short* PQ = (short*)(ws + off); off += (size_t)N_NODES * PQ_LD * 2;    // 51.2 MB
  unsigned int* es = (unsigned int*)(ws + off); off += (size_t)E_EDGES * 4;
  int* cnt    = (int*)(ws + off); off += (size_t)NSCAN * 4;
  int* offA   = (int*)(ws + off); off += (size_t)NSCAN * 4;
  int* bsum   = (int*)(ws + off); off += 256 * 4;
  int* bsumEx = (int*)(ws + off); off += 256 * 4;
  // total ~97 MB; R9 proved ws_size >= ~121 MB, but keep the guard

  if (ws_size < off){
    sentinel_kernel<<<(N_NODES * DMSG + 255) / 256, 256, 0, stream>>>((float*)d_out);
    return;
  }

  prep_kernel<<<(N_NODES * 18 + 255) / 256, 256, 0, stream>>>(x, deg, cnt, hbuf);
  pack_hist_kernel<<<HIST_BLOCKS + PACK_THREADS / 256, 256, 0, stream>>>(
      mW1, mW2, uW1, uW2, w1pq, w2m, w1u, w2u, ei, cnt);
  scan1_kernel<<<NBLK_SCAN, 256, 0, stream>>>(cnt, offA, bsum);
  scan2_kernel<<<1, 256, 0, stream>>>(bsum, bsumEx);
  pq_scatter_kernel<<<PQ_BLOCKS + HIST_BLOCKS, 256, 0, stream>>>(
      hbuf, w1pq, mb1, PQ, ei, offA, bsumEx, es);
  hsum_kernel<<<(N_NODES + 3) / 4, 256, 0, stream>>>(PQ, es, cnt, offA, bsumEx, HsumB);
  node2_kernel<<<(N_NODES + 63) / 64, 256, 0, stream>>>(hbuf, HsumB, cnt, w2m, mb2,
                                                        w1u, ub1, w2u, ub2,
                                                        (float*)d_out);
}